// Round 2
// baseline (53.744 us; speedup 1.0000x reference)
//
#include <hip/hip_runtime.h>
#include <math.h>

#define TWO_PI_F 6.2831853071795864769f

// Single fused kernel. One wave (64 lanes) per event:
//  - lanes 0-31 / 32-63 run a cooperative 32-ary search for the history
//    window [lo, hi) (obs_t sorted) -> 3 dependent load rounds, not 26.
//  - all 64 lanes accumulate the diffusion kernel over [lo, hi).
//  - F term per event is a geometric series -> closed form (2 exps).
//  - per-block partials + atomic ticket; last block reduces and writes out.
__global__ __launch_bounds__(256) void etas_fused(
    const float* __restrict__ t, const float2* __restrict__ xy,
    const float* __restrict__ pL0, const float* __restrict__ pC,
    const float* __restrict__ pBe, const float* __restrict__ pSx,
    const float* __restrict__ pSy, const float* __restrict__ pArea,
    const int* __restrict__ pnd, const int* __restrict__ pkpt,
    unsigned* __restrict__ ticket, float* __restrict__ partL,
    float* __restrict__ partF, float* __restrict__ out, int n)
{
    const int wave = threadIdx.x >> 6;
    const int lane = threadIdx.x & 63;
    const int ev   = (blockIdx.x << 2) + wave;

    __shared__ float sL[4], sF[4];
    __shared__ int   sLast;

    const float L0 = pL0[0], C = pC[0], Beta = pBe[0];
    const float Sx = pSx[0], Sy = pSy[0];
    const int   nd = pnd[0], kpt = pkpt[0];

    float logl = 0.f, fc = 0.f;
    if (ev < n) {
        const float  ti = t[ev];
        const float2 pi = xy[ev];
        const float  tlo = ti - (float)kpt;

        // dual cooperative lower_bound: half-wave 0 -> tlo, half-wave 1 -> ti
        const int   halfLane = lane & 31;
        const bool  hiHalf   = lane >= 32;
        const float target   = hiHalf ? ti : tlo;
        int l = 0, r = n;
        while (l < r) {
            int seg = (r - l + 31) >> 5;             // ceil(span/32)
            int idx = l + halfLane * seg;
            bool cond = (idx < r) && (t[idx] < target);
            unsigned long long bal = __ballot(cond);
            unsigned my = hiHalf ? (unsigned)(bal >> 32) : (unsigned)bal;
            int c = __popc(my);
            if (c == 0) { r = l; }
            else {
                int nl = l + (c - 1) * seg + 1;
                int nr = l + c * seg; if (nr > r) nr = r;
                l = nl; r = nr;
            }
        }
        const int lo = __shfl(l, 0, 64);
        const int hi = __shfl(l, 32, 64);

        const float iSx2 = 1.f / (Sx * Sx), iSy2 = 1.f / (Sy * Sy);
        float acc = 0.f;
        #pragma unroll 4
        for (int j = lo + lane; j < hi; j += 64) {
            float  dt  = ti - t[j];                  // integer-valued, (0, kpt]
            float  idt = 1.f / dt;
            float2 pj  = xy[j];
            float  dx  = pi.x - pj.x, dy = pi.y - pj.y;
            float  arg = -Beta * dt - 0.5f * idt * (dx * dx * iSx2 + dy * dy * iSy2);
            acc += idt * __expf(arg);
        }
        for (int off = 32; off > 0; off >>= 1) acc += __shfl_down(acc, off, 64);

        if (lane == 0) {
            float lam = (ti <= 1.0f) ? L0 : acc * (C / (TWO_PI_F * Sx * Sy));
            logl = __logf(lam);
            // F contribution: C * sum_{k=1..m} e^{-Beta k}, m = min(kpt, nd - day)
            int m = nd - (int)ti; if (m > kpt) m = kpt; if (m < 0) m = 0;
            float rr  = __expf(-Beta);
            float geo = rr * (1.f - __expf(-Beta * (float)m)) / (1.f - rr);
            fc = C * geo;
        }
    }

    if (lane == 0) { sL[wave] = logl; sF[wave] = fc; }
    __syncthreads();
    if (threadIdx.x == 0) {
        partL[blockIdx.x] = sL[0] + sL[1] + sL[2] + sL[3];
        partF[blockIdx.x] = sF[0] + sF[1] + sF[2] + sF[3];
        __threadfence();                              // flush partials device-wide
        unsigned tk = atomicAdd(ticket, 1u);
        sLast = (tk == gridDim.x - 1);
    }
    __syncthreads();

    if (sLast) {
        if (threadIdx.x == 0) __threadfence();        // acquire: invalidate stale cache
        __syncthreads();
        float a = 0.f, b = 0.f;
        const int nb = (int)gridDim.x;
        for (int i = threadIdx.x; i < nb; i += 256) { a += partL[i]; b += partF[i]; }
        __shared__ float rA[256], rB[256];
        rA[threadIdx.x] = a; rB[threadIdx.x] = b;
        __syncthreads();
        for (int s = 128; s > 0; s >>= 1) {
            if (threadIdx.x < s) {
                rA[threadIdx.x] += rA[threadIdx.x + s];
                rB[threadIdx.x] += rB[threadIdx.x + s];
            }
            __syncthreads();
        }
        if (threadIdx.x == 0) {
            float lams1 = rA[0];
            float lams2 = L0 * pArea[0] * (float)nd + rB[0];
            out[0] = lams1 - lams2;
            out[1] = lams1;
            out[2] = lams2;
        }
    }
}

extern "C" void kernel_launch(void* const* d_in, const int* in_sizes, int n_in,
                              void* d_out, int out_size, void* d_ws, size_t ws_size,
                              hipStream_t stream)
{
    const float*  obs_t  = (const float*)d_in[0];
    const float2* obs_xy = (const float2*)d_in[1];
    const float*  pL0    = (const float*)d_in[2];
    const float*  pC     = (const float*)d_in[3];
    const float*  pBe    = (const float*)d_in[4];
    const float*  pSx    = (const float*)d_in[5];
    const float*  pSy    = (const float*)d_in[6];
    const float*  pArea  = (const float*)d_in[7];
    const int*    pnd    = (const int*)d_in[8];
    const int*    pkpt   = (const int*)d_in[9];

    const int n  = in_sizes[0];
    const int nb = (n + 3) / 4;                      // 4 events (waves) per block

    unsigned* ticket = (unsigned*)d_ws;              // [0..3] bytes
    float*    partL  = (float*)((char*)d_ws + 16);   // [nb]
    float*    partF  = partL + nb;                   // [nb]

    hipMemsetAsync(ticket, 0, 4, stream);            // zero ticket every call
    etas_fused<<<nb, 256, 0, stream>>>(obs_t, obs_xy, pL0, pC, pBe, pSx, pSy,
                                       pArea, pnd, pkpt, ticket, partL, partF,
                                       (float*)d_out, n);
}

// Round 3
// 22.908 us; speedup vs baseline: 2.3461x; 2.3461x over previous
//
#include <hip/hip_runtime.h>
#include <math.h>

#define TWO_PI_F 6.2831853071795864769f

// Single fused kernel, NO cache fences (a __threadfence here forces an L2
// writeback of the poisoned 256MB workspace -> 192MB of HBM writes, measured
// +30us in round 2). All cross-block communication goes through device-scope
// atomics, which perform at the coherent point:
//   - partials published with atomicExch (coherent store)
//   - ordering via s_waitcnt vmcnt(0) before the ticket atomic
//   - last block reads partials with atomicAdd(p, 0.0f) (coherent, exact)
// One wave (64 lanes) per event; cooperative dual 32-ary search for the
// history window [lo, hi); closed-form geometric series for the F term.
__global__ __launch_bounds__(1024) void etas_fused(
    const float* __restrict__ t, const float2* __restrict__ xy,
    const float* __restrict__ pL0, const float* __restrict__ pC,
    const float* __restrict__ pBe, const float* __restrict__ pSx,
    const float* __restrict__ pSy, const float* __restrict__ pArea,
    const int* __restrict__ pnd, const int* __restrict__ pkpt,
    unsigned* __restrict__ ticket, float* __restrict__ partL,
    float* __restrict__ partF, float* __restrict__ out, int n)
{
    const int wave = threadIdx.x >> 6;
    const int lane = threadIdx.x & 63;
    const int ev   = (blockIdx.x << 4) + wave;      // 16 waves per block

    __shared__ float sL[16], sF[16];
    __shared__ int   sLast;

    const float L0 = pL0[0], C = pC[0], Beta = pBe[0];
    const float Sx = pSx[0], Sy = pSy[0];
    const int   nd = pnd[0], kpt = pkpt[0];

    float logl = 0.f, fc = 0.f;
    if (ev < n) {
        const float  ti = t[ev];
        const float2 pi = xy[ev];
        const float  tlo = ti - (float)kpt;

        // dual cooperative lower_bound: half-wave 0 -> tlo, half-wave 1 -> ti
        const int   halfLane = lane & 31;
        const bool  hiHalf   = lane >= 32;
        const float target   = hiHalf ? ti : tlo;
        int l = 0, r = n;
        while (l < r) {
            int seg = (r - l + 31) >> 5;             // ceil(span/32)
            int idx = l + halfLane * seg;
            bool cond = (idx < r) && (t[idx] < target);
            unsigned long long bal = __ballot(cond);
            unsigned my = hiHalf ? (unsigned)(bal >> 32) : (unsigned)bal;
            int c = __popc(my);
            if (c == 0) { r = l; }
            else {
                int nl = l + (c - 1) * seg + 1;
                int nr = l + c * seg; if (nr > r) nr = r;
                l = nl; r = nr;
            }
        }
        const int lo = __shfl(l, 0, 64);
        const int hi = __shfl(l, 32, 64);

        const float iSx2 = 1.f / (Sx * Sx), iSy2 = 1.f / (Sy * Sy);
        float acc = 0.f;
        #pragma unroll 4
        for (int j = lo + lane; j < hi; j += 64) {
            float  dt  = ti - t[j];                  // integer-valued, (0, kpt]
            float  idt = 1.f / dt;
            float2 pj  = xy[j];
            float  dx  = pi.x - pj.x, dy = pi.y - pj.y;
            float  arg = -Beta * dt - 0.5f * idt * (dx * dx * iSx2 + dy * dy * iSy2);
            acc += idt * __expf(arg);
        }
        for (int off = 32; off > 0; off >>= 1) acc += __shfl_down(acc, off, 64);

        if (lane == 0) {
            float lam = (ti <= 1.0f) ? L0 : acc * (C / (TWO_PI_F * Sx * Sy));
            logl = __logf(lam);
            // F contribution: C * sum_{k=1..m} e^{-Beta k}, m = min(kpt, nd - day)
            int m = nd - (int)ti; if (m > kpt) m = kpt; if (m < 0) m = 0;
            float rr  = __expf(-Beta);
            float geo = rr * (1.f - __expf(-Beta * (float)m)) / (1.f - rr);
            fc = C * geo;
        }
    }

    if (lane == 0) { sL[wave] = logl; sF[wave] = fc; }
    __syncthreads();
    if (threadIdx.x == 0) {
        float a = 0.f, b = 0.f;
        #pragma unroll
        for (int i = 0; i < 16; ++i) { a += sL[i]; b += sF[i]; }
        atomicExch(&partL[blockIdx.x], a);           // coherent publish, no fence
        atomicExch(&partF[blockIdx.x], b);
        asm volatile("s_waitcnt vmcnt(0)" ::: "memory"); // partials performed
        unsigned tk = atomicAdd(ticket, 1u);
        sLast = (tk == gridDim.x - 1);
    }
    __syncthreads();

    if (sLast) {
        const int nbk = (int)gridDim.x;
        float a = 0.f, b = 0.f;
        for (int i = threadIdx.x; i < nbk; i += 1024) {
            a += atomicAdd(&partL[i], 0.0f);         // coherent read, exact
            b += atomicAdd(&partF[i], 0.0f);
        }
        for (int off = 32; off > 0; off >>= 1) {
            a += __shfl_down(a, off, 64);
            b += __shfl_down(b, off, 64);
        }
        if (lane == 0) { sL[wave] = a; sF[wave] = b; }
        __syncthreads();
        if (threadIdx.x == 0) {
            float A = 0.f, B = 0.f;
            #pragma unroll
            for (int i = 0; i < 16; ++i) { A += sL[i]; B += sF[i]; }
            float lams1 = A;
            float lams2 = L0 * pArea[0] * (float)nd + B;
            out[0] = lams1 - lams2;
            out[1] = lams1;
            out[2] = lams2;
        }
    }
}

extern "C" void kernel_launch(void* const* d_in, const int* in_sizes, int n_in,
                              void* d_out, int out_size, void* d_ws, size_t ws_size,
                              hipStream_t stream)
{
    const float*  obs_t  = (const float*)d_in[0];
    const float2* obs_xy = (const float2*)d_in[1];
    const float*  pL0    = (const float*)d_in[2];
    const float*  pC     = (const float*)d_in[3];
    const float*  pBe    = (const float*)d_in[4];
    const float*  pSx    = (const float*)d_in[5];
    const float*  pSy    = (const float*)d_in[6];
    const float*  pArea  = (const float*)d_in[7];
    const int*    pnd    = (const int*)d_in[8];
    const int*    pkpt   = (const int*)d_in[9];

    const int n  = in_sizes[0];
    const int nb = (n + 15) / 16;                    // 16 events (waves) per block

    unsigned* ticket = (unsigned*)d_ws;              // 4 bytes
    float*    partL  = (float*)((char*)d_ws + 16);   // [nb]
    float*    partF  = partL + nb;                   // [nb]

    hipMemsetAsync(ticket, 0, 4, stream);            // zero ticket every call
    etas_fused<<<nb, 1024, 0, stream>>>(obs_t, obs_xy, pL0, pC, pBe, pSx, pSy,
                                        pArea, pnd, pkpt, ticket, partL, partF,
                                        (float*)d_out, n);
}

// Round 4
// 16.379 us; speedup vs baseline: 3.2812x; 1.3986x over previous
//
#include <hip/hip_runtime.h>
#include <math.h>

#define TWO_PI_F 6.2831853071795864769f

// Two plain kernels, no fences, no atomics, no memset node.
// k1: one wave (64 lanes) per event; cooperative dual 32-ary search finds the
//     history window [lo,hi) in ~4 dependent gather rounds; fused diffusion
//     kernel accumulation; closed-form geometric series for the F term.
//     Per-block partials via plain stores (end-of-kernel release makes them
//     visible to k2 -- no __threadfence, which round 2 showed costs ~30us).
// k2: single block reduces the 512 partials and writes (loglik, lams1, lams2).
__global__ __launch_bounds__(1024) void etas_part(
    const float* __restrict__ t, const float2* __restrict__ xy,
    const float* __restrict__ pL0, const float* __restrict__ pC,
    const float* __restrict__ pBe, const float* __restrict__ pSx,
    const float* __restrict__ pSy,
    const int* __restrict__ pnd, const int* __restrict__ pkpt,
    float* __restrict__ partL, float* __restrict__ partF, int n)
{
    const int wave = threadIdx.x >> 6;
    const int lane = threadIdx.x & 63;
    const int ev   = (blockIdx.x << 4) + wave;      // 16 waves per block

    __shared__ float sL[16], sF[16];

    const float L0 = pL0[0], C = pC[0], Beta = pBe[0];
    const float Sx = pSx[0], Sy = pSy[0];
    const int   nd = pnd[0], kpt = pkpt[0];

    float logl = 0.f, fc = 0.f;
    if (ev < n) {
        const float  ti = t[ev];
        const float2 pi = xy[ev];
        const float  tlo = ti - (float)kpt;

        // dual cooperative lower_bound: half-wave 0 -> tlo, half-wave 1 -> ti
        const int   halfLane = lane & 31;
        const bool  hiHalf   = lane >= 32;
        const float target   = hiHalf ? ti : tlo;
        int l = 0, r = n;
        while (l < r) {
            int seg = (r - l + 31) >> 5;             // ceil(span/32)
            int idx = l + halfLane * seg;
            bool cond = (idx < r) && (t[idx] < target);
            unsigned long long bal = __ballot(cond);
            unsigned my = hiHalf ? (unsigned)(bal >> 32) : (unsigned)bal;
            int c = __popc(my);
            if (c == 0) { r = l; }
            else {
                int nl = l + (c - 1) * seg + 1;
                int nr = l + c * seg; if (nr > r) nr = r;
                l = nl; r = nr;
            }
        }
        const int lo = __shfl(l, 0, 64);
        const int hi = __shfl(l, 32, 64);

        const float iSx2 = 1.f / (Sx * Sx), iSy2 = 1.f / (Sy * Sy);
        float acc = 0.f;
        #pragma unroll 4
        for (int j = lo + lane; j < hi; j += 64) {
            float  dt  = ti - t[j];                  // integer-valued, (0, kpt]
            float  idt = 1.f / dt;
            float2 pj  = xy[j];
            float  dx  = pi.x - pj.x, dy = pi.y - pj.y;
            float  arg = -Beta * dt - 0.5f * idt * (dx * dx * iSx2 + dy * dy * iSy2);
            acc += idt * __expf(arg);
        }
        for (int off = 32; off > 0; off >>= 1) acc += __shfl_down(acc, off, 64);

        if (lane == 0) {
            float lam = (ti <= 1.0f) ? L0 : acc * (C / (TWO_PI_F * Sx * Sy));
            logl = __logf(lam);
            // F contribution: C * sum_{k=1..m} e^{-Beta k}, m = min(kpt, nd - day)
            int m = nd - (int)ti; if (m > kpt) m = kpt; if (m < 0) m = 0;
            float rr  = __expf(-Beta);
            float geo = rr * (1.f - __expf(-Beta * (float)m)) / (1.f - rr);
            fc = C * geo;
        }
    }

    if (lane == 0) { sL[wave] = logl; sF[wave] = fc; }
    __syncthreads();
    if (threadIdx.x == 0) {
        float a = 0.f, b = 0.f;
        #pragma unroll
        for (int i = 0; i < 16; ++i) { a += sL[i]; b += sF[i]; }
        partL[blockIdx.x] = a;                       // plain store; kernel-end
        partF[blockIdx.x] = b;                       // release publishes it
    }
}

__global__ __launch_bounds__(256) void etas_fin(
    const float* __restrict__ partL, const float* __restrict__ partF, int nb,
    const float* __restrict__ pL0, const float* __restrict__ pArea,
    const int* __restrict__ pnd, float* __restrict__ out)
{
    const int tid = threadIdx.x;
    float a = 0.f, b = 0.f;
    for (int i = tid; i < nb; i += 256) { a += partL[i]; b += partF[i]; }
    for (int off = 32; off > 0; off >>= 1) {
        a += __shfl_down(a, off, 64);
        b += __shfl_down(b, off, 64);
    }
    __shared__ float sA[4], sB[4];
    if ((tid & 63) == 0) { sA[tid >> 6] = a; sB[tid >> 6] = b; }
    __syncthreads();
    if (tid == 0) {
        float A = sA[0] + sA[1] + sA[2] + sA[3];
        float B = sB[0] + sB[1] + sB[2] + sB[3];
        float lams1 = A;
        float lams2 = pL0[0] * pArea[0] * (float)pnd[0] + B;
        out[0] = lams1 - lams2;
        out[1] = lams1;
        out[2] = lams2;
    }
}

extern "C" void kernel_launch(void* const* d_in, const int* in_sizes, int n_in,
                              void* d_out, int out_size, void* d_ws, size_t ws_size,
                              hipStream_t stream)
{
    const float*  obs_t  = (const float*)d_in[0];
    const float2* obs_xy = (const float2*)d_in[1];
    const float*  pL0    = (const float*)d_in[2];
    const float*  pC     = (const float*)d_in[3];
    const float*  pBe    = (const float*)d_in[4];
    const float*  pSx    = (const float*)d_in[5];
    const float*  pSy    = (const float*)d_in[6];
    const float*  pArea  = (const float*)d_in[7];
    const int*    pnd    = (const int*)d_in[8];
    const int*    pkpt   = (const int*)d_in[9];

    const int n  = in_sizes[0];
    const int nb = (n + 15) / 16;                    // 16 events (waves) per block

    float* partL = (float*)d_ws;                     // [nb]
    float* partF = partL + nb;                       // [nb]

    etas_part<<<nb, 1024, 0, stream>>>(obs_t, obs_xy, pL0, pC, pBe, pSx, pSy,
                                       pnd, pkpt, partL, partF, n);
    etas_fin<<<1, 256, 0, stream>>>(partL, partF, nb, pL0, pArea, pnd,
                                    (float*)d_out);
}